// Round 13
// baseline (544.801 us; speedup 1.0000x reference)
//
#include <hip/hip_runtime.h>
#include <hip/hip_bf16.h>
#include <cstdint>

static constexpr int NN = 100000;     // nodes
static constexpr int NE = 800000;     // edges (without self loops)
static constexpr int EP = NE + NN;    // edges incl. self loops
static constexpr int NB = (NN + 255) / 256;  // scan blocks

typedef unsigned short ushort;
typedef __attribute__((ext_vector_type(8))) short short8;
typedef __attribute__((ext_vector_type(8))) ushort ushort8v;
typedef __attribute__((ext_vector_type(4))) float f32x4;

__device__ __forceinline__ float leaky(float x) { return x > 0.f ? x : 0.2f * x; }

// float -> bf16 bits (RNE)
__device__ __forceinline__ ushort f2bf(float f) {
    unsigned int u = __float_as_uint(f);
    u += 0x7fffu + ((u >> 16) & 1u);
    return (ushort)(u >> 16);
}
__device__ __forceinline__ float bf2f(ushort h) {
    return __uint_as_float(((unsigned int)h) << 16);
}

// async global->LDS 16B copy: per-lane global src; LDS dest = base + lane*16
// (our per-lane pointers are exactly that). Counted by vmcnt.
__device__ __forceinline__ void gload16(const void* g, void* l) {
    __builtin_amdgcn_global_load_lds((__attribute__((address_space(1))) void*)g,
                                     (__attribute__((address_space(3))) void*)l,
                                     16, 0, 0);
}

// T4 counted-vmcnt barrier: B-stage (oldest VMEM ops) must be complete;
// the 4 newest (A register prefetch) stay in flight across the barrier.
__device__ __forceinline__ void waitbar4() {
    asm volatile("s_waitcnt vmcnt(4)" ::: "memory");
    __builtin_amdgcn_s_barrier();
    __builtin_amdgcn_sched_barrier(0);
}

// ---------------------------------------------------------------------------
// Weight pre-tiling: W (virtual concat [Wa | Wb], K x NT, row-major) ->
//   Whi/Wlo: [K/32][NT][32] bf16 (hi + lo split) — the MFMA B-frag layout.
// ---------------------------------------------------------------------------
__global__ void pretile_kernel(const float* __restrict__ Wa, const float* __restrict__ Wb,
                               int K, int CS, int NT,
                               ushort* __restrict__ Whi, ushort* __restrict__ Wlo)
{
    int idx = blockIdx.x * 256 + threadIdx.x;
    if (idx >= K * NT) return;
    int k = idx / NT, c = idx - k * NT;
    float v = (c < CS) ? Wa[(size_t)k * CS + c] : Wb[(size_t)k * (NT - CS) + (c - CS)];
    ushort h = f2bf(v);
    ushort l = f2bf(v - bf2f(h));
    size_t o = ((size_t)(k >> 5) * NT + c) * 32 + (k & 31);
    Whi[o] = h; Wlo[o] = l;
}

// ---------------------------------------------------------------------------
// Split-bf16 MFMA GEMM (3-pass hi/lo, ~fp32 accuracy), "wave-private rows"
// + T4 counted-vmcnt pipeline.
//   RESB=false (L0): B double-buffered in LDS, one waitbar4 per k-tile.
//   RESB=true  (L1/L2/JK): ENTIRE B resident in LDS (fits for K*N <= 320*64
//     or 128*128) — staged once in the prologue, ONE barrier total, k-loop
//     is barrier-free (waves fully independent; only A-prefetch waits).
//   Y1BF: store Y1 (xh consumed by gather-SpMM) as bf16.
// ---------------------------------------------------------------------------
template<int KTOT, int NTOT, int K1, int K2, int CSPLIT, int BIAS_OFF,
         int AHH, int ACC, int ATTN, bool ASPLIT, bool Y1BF, bool RESB, int MINW>
__global__ __launch_bounds__(256, MINW)
void gemm_mfma(const void* __restrict__ X1, const void* __restrict__ X1b,
               const void* __restrict__ X2, const void* __restrict__ X2b,
               const void* __restrict__ X3, const void* __restrict__ X3b,
               int ldx1, int ldx2, int ldx3,
               const ushort* __restrict__ Wthi, const ushort* __restrict__ Wtlo,
               const float* __restrict__ bias,
               void* __restrict__ Y1, float* __restrict__ Y2, int ldy1, int ldy2,
               float* __restrict__ als, float* __restrict__ ald,
               const float* __restrict__ a_src, const float* __restrict__ a_dst,
               int n)
{
    constexpr int NKT  = KTOT / 32;
    constexpr int NF   = NTOT / 16;   // col frags per wave (spans full N)
    constexpr int NBUF = RESB ? NKT : 2;

    __shared__ ushort Bh[NBUF * NTOT * 32], Bl[NBUF * NTOT * 32];

    const int t = threadIdx.x, l = t & 63, w = t >> 6;
    const int lc = l & 15, lq = l >> 4;
    const int wrow = blockIdx.x * 128 + w * 32;   // wave's private 32 rows

    f32x4 acc[2][NF];
#pragma unroll
    for (int mf = 0; mf < 2; ++mf)
#pragma unroll
        for (int nf = 0; nf < NF; ++nf)
            acc[mf][nf] = (f32x4){0.f, 0.f, 0.f, 0.f};

    int arow[2], rcl[2];
#pragma unroll
    for (int mf = 0; mf < 2; ++mf) {
        arow[mf] = wrow + mf * 16 + lc;
        rcl[mf]  = arow[mf] < n ? arow[mf] : (n - 1);   // clamp: uniform issue
    }

    // A register double-buffer (named slots; static under full unroll)
    short8 A0h[2], A0l[2], A1h[2], A1l[2];   // split path
    float4 F0[2][2], F1[2][2];               // f32 path (raw)

    auto loadA = [&](int kt, short8 (&dh)[2], short8 (&dl)[2], float4 (&df)[2][2]) {
        const int k0 = kt * 32;
        const void* xp; const void* xq; int ldx, koff;
        if (k0 < K1)      { xp = X1; xq = X1b; ldx = ldx1; koff = k0; }
        else if (k0 < K2) { xp = X2; xq = X2b; ldx = ldx2; koff = k0 - K1; }
        else              { xp = X3; xq = X3b; ldx = ldx3; koff = k0 - K2; }
        if constexpr (ASPLIT) {
            const ushort* ph = (const ushort*)xp;
            const ushort* pl = (const ushort*)xq;
#pragma unroll
            for (int mf = 0; mf < 2; ++mf) {
                size_t o = (size_t)rcl[mf] * ldx + koff + lq * 8;
                dh[mf] = *(const short8*)&ph[o];
                dl[mf] = *(const short8*)&pl[o];
            }
        } else {
            const float* pf = (const float*)xp;
#pragma unroll
            for (int mf = 0; mf < 2; ++mf) {
                size_t o = (size_t)rcl[mf] * ldx + koff + lq * 8;
                df[mf][0] = *(const float4*)&pf[o];
                df[mf][1] = *(const float4*)&pf[o + 4];
            }
        }
    };

    auto stageB = [&](int kt, int buf) {
        constexpr int UN = NTOT * 4;           // 16B units per (hi or lo) tile
#pragma unroll
        for (int s = 0; s < UN / 256; ++s) {
            int unit = s * 256 + t;            // = kq*NTOT + col (linear)
            int col  = unit & (NTOT - 1);
            int kq   = unit / NTOT;
            size_t go = ((size_t)kt * NTOT + col) * 32 + kq * 8;
            gload16(&Wthi[go], &Bh[(size_t)buf * NTOT * 32 + unit * 8]);
            gload16(&Wtlo[go], &Bl[(size_t)buf * NTOT * 32 + unit * 8]);
        }
    };

    // prologue: stage oldest, then A prefetch, counted wait
    if constexpr (RESB) {
#pragma unroll
        for (int kt2 = 0; kt2 < NKT; ++kt2) stageB(kt2, kt2);   // all of B
    } else {
        stageB(0, 0);
    }
    __builtin_amdgcn_sched_barrier(0);         // pin issue order: B before A
    loadA(0, A0h, A0l, F0);
    waitbar4();                                // B in LDS; A(0) in flight

#pragma unroll
    for (int kt = 0; kt < NKT; ++kt) {
        if (kt + 1 < NKT) {
            if constexpr (!RESB) {
                stageB(kt + 1, (kt + 1) & 1);  // oldest VMEM this tile
                __builtin_amdgcn_sched_barrier(0); // keep A-loads newest
            }
            if (((kt + 1) & 1) == 0) loadA(kt + 1, A0h, A0l, F0);
            else                     loadA(kt + 1, A1h, A1l, F1);
        }

        short8 ah[2], al[2];
        if constexpr (ASPLIT) {
            if ((kt & 1) == 0) { ah[0]=A0h[0]; ah[1]=A0h[1]; al[0]=A0l[0]; al[1]=A0l[1]; }
            else               { ah[0]=A1h[0]; ah[1]=A1h[1]; al[0]=A1l[0]; al[1]=A1l[1]; }
        } else {
            const auto& Fc = (kt & 1) ? F1 : F0;
#pragma unroll
            for (int mf = 0; mf < 2; ++mf) {
                short8 h8, l8;
#pragma unroll
                for (int e = 0; e < 8; ++e) {
                    float f = (e < 4) ? (&Fc[mf][0].x)[e] : (&Fc[mf][1].x)[e - 4];
                    ushort hh = f2bf(f);
                    h8[e] = (short)hh;
                    l8[e] = (short)f2bf(f - bf2f(hh));
                }
                ah[mf] = h8; al[mf] = l8;
            }
        }

        const int cb = RESB ? kt : (kt & 1);
#pragma unroll
        for (int nf = 0; nf < NF; ++nf) {
            int bslot = lq * NTOT + nf * 16 + lc;
            short8 bh = *(const short8*)&Bh[(size_t)cb * NTOT * 32 + bslot * 8];
            short8 bl = *(const short8*)&Bl[(size_t)cb * NTOT * 32 + bslot * 8];
#pragma unroll
            for (int mf = 0; mf < 2; ++mf) {
                acc[mf][nf] = __builtin_amdgcn_mfma_f32_16x16x32_bf16(ah[mf], bh, acc[mf][nf], 0, 0, 0);
                acc[mf][nf] = __builtin_amdgcn_mfma_f32_16x16x32_bf16(ah[mf], bl, acc[mf][nf], 0, 0, 0);
                acc[mf][nf] = __builtin_amdgcn_mfma_f32_16x16x32_bf16(al[mf], bh, acc[mf][nf], 0, 0, 0);
            }
        }
        if constexpr (!RESB) {
            if (kt + 1 < NKT) waitbar4();   // B(t+1) landed; A(t+1) flying
        }
    }

    // ---- attention-logit epilogue (f32 accumulator — full precision) ----
    if constexpr (AHH > 0) {
        constexpr int FPH = ACC / 16;     // frags per head
        constexpr int NG  = ATTN / ACC;   // heads (all live in this wave)
#pragma unroll
        for (int g = 0; g < NG; ++g) {
#pragma unroll
            for (int mf = 0; mf < 2; ++mf) {
                float ps[4] = {0.f, 0.f, 0.f, 0.f};
                float pd[4] = {0.f, 0.f, 0.f, 0.f};
#pragma unroll
                for (int j = 0; j < FPH; ++j) {
                    int col = g * ACC + j * 16 + lc;
                    float av = a_src[col], dv = a_dst[col];
#pragma unroll
                    for (int r = 0; r < 4; ++r) {
                        ps[r] = fmaf(acc[mf][g * FPH + j][r], av, ps[r]);
                        pd[r] = fmaf(acc[mf][g * FPH + j][r], dv, pd[r]);
                    }
                }
#pragma unroll
                for (int off = 1; off < 16; off <<= 1)
#pragma unroll
                    for (int r = 0; r < 4; ++r) {
                        ps[r] += __shfl_xor(ps[r], off);
                        pd[r] += __shfl_xor(pd[r], off);
                    }
                if (lc == 0) {
#pragma unroll
                    for (int r = 0; r < 4; ++r) {
                        int row = wrow + mf * 16 + lq * 4 + r;
                        if (row < n) {
                            als[(size_t)row * AHH + g] = ps[r];
                            ald[(size_t)row * AHH + g] = pd[r];
                        }
                    }
                }
            }
        }
    }

    // ---- store (+ bias for cols >= BIAS_OFF); Y1 optionally bf16 ----
#pragma unroll
    for (int mf = 0; mf < 2; ++mf) {
        int rb4 = wrow + mf * 16 + lq * 4;
#pragma unroll
        for (int nf = 0; nf < NF; ++nf) {
            int col = nf * 16 + lc;
            float bv = 0.f;
            if constexpr (BIAS_OFF < NTOT) {
                if (col >= BIAS_OFF) bv = bias[col - BIAS_OFF];
            }
#pragma unroll
            for (int r = 0; r < 4; ++r) {
                int row = rb4 + r;
                if (row < n) {
                    float v = acc[mf][nf][r] + bv;
                    if (col < CSPLIT) {
                        if constexpr (Y1BF)
                            ((ushort*)Y1)[(size_t)row * ldy1 + col] = f2bf(v);
                        else
                            ((float*)Y1)[(size_t)row * ldy1 + col] = v;
                    } else {
                        Y2[(size_t)row * ldy2 + (col - CSPLIT)] = v;
                    }
                }
            }
        }
    }
}

// ---------------------------------------------------------------------------
// CSR build: histogram -> block sums -> scan sums -> per-block scan -> fill
// ---------------------------------------------------------------------------
__global__ void deg_kernel(const int* __restrict__ ei, int* __restrict__ deg)
{
    int t = blockIdx.x * blockDim.x + threadIdx.x;
    if (t < NE) atomicAdd(&deg[ei[NE + t]], 1);   // dst of edge t
}

__global__ void block_sum_kernel(const int* __restrict__ deg, int* __restrict__ bsum)
{
    int node = blockIdx.x * 256 + threadIdx.x;
    int v = (node < NN) ? deg[node] + 1 : 0;      // +1 = self loop
#pragma unroll
    for (int off = 32; off > 0; off >>= 1) v += __shfl_down(v, off);
    __shared__ int sh[4];
    if ((threadIdx.x & 63) == 0) sh[threadIdx.x >> 6] = v;
    __syncthreads();
    if (threadIdx.x == 0) bsum[blockIdx.x] = sh[0] + sh[1] + sh[2] + sh[3];
}

__global__ void scan_sums_kernel(const int* __restrict__ bsum, int* __restrict__ bsumx,
                                 int* __restrict__ rowptr)
{
    if (threadIdx.x == 0) {
        int run = 0;
        for (int i = 0; i < NB; ++i) { bsumx[i] = run; run += bsum[i]; }
        rowptr[NN] = run;    // == EP
    }
}

__global__ void scan_blocks_kernel(const int* __restrict__ deg, const int* __restrict__ bsumx,
                                   int* __restrict__ rowptr, int* __restrict__ cursor)
{
    __shared__ int sh[256];
    int node = blockIdx.x * 256 + threadIdx.x;
    int v = (node < NN) ? deg[node] + 1 : 0;
    sh[threadIdx.x] = v;
    __syncthreads();
#pragma unroll
    for (int off = 1; off < 256; off <<= 1) {
        int tv = (threadIdx.x >= off) ? sh[threadIdx.x - off] : 0;
        __syncthreads();
        sh[threadIdx.x] += tv;
        __syncthreads();
    }
    if (node < NN) {
        int excl = bsumx[blockIdx.x] + sh[threadIdx.x] - v;
        rowptr[node] = excl;
        cursor[node] = excl;
    }
}

__global__ void fill_kernel(const int* __restrict__ ei, int* __restrict__ cursor,
                            int* __restrict__ csr_src)
{
    int t = blockIdx.x * blockDim.x + threadIdx.x;
    if (t >= EP) return;
    int s, d;
    if (t < NE) { s = ei[t]; d = ei[NE + t]; }
    else        { s = d = t - NE; }
    int pos = atomicAdd(&cursor[d], 1);
    csr_src[pos] = s;
}

// ---------------------------------------------------------------------------
// Softmax stats + normalized edge weights (packed bf16). ONE THREAD PER NODE.
// ---------------------------------------------------------------------------
template<int HH>
__global__ __launch_bounds__(256)
void attn_weights_kernel(const int* __restrict__ rowptr, const int* __restrict__ csr_src,
                         const float* __restrict__ als, const float* __restrict__ ald,
                         ushort* __restrict__ wq, int n)
{
    int node = blockIdx.x * 256 + threadIdx.x;
    if (node >= n) return;
    const int e0 = rowptr[node], e1 = rowptr[node + 1];
    float aldv[HH], m[HH], d[HH];
#pragma unroll
    for (int h = 0; h < HH; ++h) { m[h] = -1e30f; d[h] = 0.f; }
    if constexpr (HH == 4) {
        float4 a = *(const float4*)&ald[(size_t)node * 4];
        aldv[0] = a.x; aldv[1] = a.y; aldv[2] = a.z; aldv[3] = a.w;
    } else {
        aldv[0] = ald[node];
    }
    for (int e = e0; e < e1; ++e) {
        int s = csr_src[e];
        float av[HH];
        if constexpr (HH == 4) {
            float4 a = *(const float4*)&als[(size_t)s * 4];
            av[0] = a.x; av[1] = a.y; av[2] = a.z; av[3] = a.w;
        } else {
            av[0] = als[s];
        }
#pragma unroll
        for (int h = 0; h < HH; ++h) {
            float sc = leaky(av[h] + aldv[h]);
            float nm = fmaxf(m[h], sc);
            d[h] = d[h] * __expf(m[h] - nm) + __expf(sc - nm);
            m[h] = nm;
        }
    }
#pragma unroll
    for (int h = 0; h < HH; ++h) d[h] = 1.f / d[h];
    for (int e = e0; e < e1; ++e) {
        int s = csr_src[e];
        float av[HH];
        if constexpr (HH == 4) {
            float4 a = *(const float4*)&als[(size_t)s * 4];
            av[0] = a.x; av[1] = a.y; av[2] = a.z; av[3] = a.w;
        } else {
            av[0] = als[s];
        }
        if constexpr (HH == 4) {
            uint2 o;
            unsigned int w0 = f2bf(__expf(leaky(av[0] + aldv[0]) - m[0]) * d[0]);
            unsigned int w1 = f2bf(__expf(leaky(av[1] + aldv[1]) - m[1]) * d[1]);
            unsigned int w2 = f2bf(__expf(leaky(av[2] + aldv[2]) - m[2]) * d[2]);
            unsigned int w3 = f2bf(__expf(leaky(av[3] + aldv[3]) - m[3]) * d[3]);
            o.x = w0 | (w1 << 16);
            o.y = w2 | (w3 << 16);
            *(uint2*)&wq[(size_t)e * 4] = o;
        } else {
            wq[e] = f2bf(__expf(leaky(av[0] + aldv[0]) - m[0]) * d[0]);
        }
    }
}

// ---------------------------------------------------------------------------
// Weighted gather-SpMM + fused epilogue. ONE WAVE PER NODE, lane = channel
// pair. xh gathered as bf16; wq read as bf16. 4-edge unroll for load ILP.
// Output written as pre-split hi/lo bf16. Residual f32 or split (RESSPLIT).
// ---------------------------------------------------------------------------
template<int HH, int CC, bool DOELU, bool RESSPLIT>
__global__ __launch_bounds__(256)
void spmm_kernel(const int* __restrict__ rowptr, const int* __restrict__ csr_src,
                 const ushort* __restrict__ xh, const ushort* __restrict__ wq,
                 const float* __restrict__ b,
                 const float* __restrict__ resf,
                 const ushort* __restrict__ resh, const ushort* __restrict__ resl,
                 ushort* __restrict__ outh, ushort* __restrict__ outl, int n)
{
    constexpr int HCL = HH * CC;
    constexpr int CPL = HCL / 64;                 // channels per lane (2 or 1)
    const int l = threadIdx.x & 63;
    const int node = blockIdx.x * 4 + (threadIdx.x >> 6);
    if (node >= n) return;
    const int c = l * CPL;
    const int h = c / CC;
    const int e0 = rowptr[node], e1 = rowptr[node + 1];

    float a0[CPL], a1[CPL];
#pragma unroll
    for (int j = 0; j < CPL; ++j) { a0[j] = 0.f; a1[j] = 0.f; }

    auto gather = [&](int e, float* accv) {
        int s = csr_src[e];
        float w0 = bf2f(wq[(size_t)e * HH + h]);
        if constexpr (CPL == 2) {
            unsigned int uv = *(const unsigned int*)&xh[(size_t)s * HCL + c];
            accv[0] = fmaf(w0, bf2f((ushort)(uv & 0xffffu)), accv[0]);
            accv[1] = fmaf(w0, bf2f((ushort)(uv >> 16)), accv[1]);
        } else {
            accv[0] = fmaf(w0, bf2f(xh[(size_t)s * HCL + c]), accv[0]);
        }
    };

    int e = e0;
    for (; e + 3 < e1; e += 4) {
        gather(e, a0); gather(e + 1, a1);
        gather(e + 2, a0); gather(e + 3, a1);
    }
    for (; e < e1; ++e) gather(e, a0);

#pragma unroll
    for (int j = 0; j < CPL; ++j) {
        size_t idx = (size_t)node * HCL + c + j;
        float rv;
        if constexpr (RESSPLIT) rv = bf2f(resh[idx]) + bf2f(resl[idx]);
        else                    rv = resf[idx];
        float v = a0[j] + a1[j] + b[c + j] + rv;
        if (DOELU) v = v > 0.f ? v : (__expf(v) - 1.f);
        ushort hh = f2bf(v);
        outh[idx] = hh;
        outl[idx] = f2bf(v - bf2f(hh));
    }
}

// ---------------------------------------------------------------------------
extern "C" void kernel_launch(void* const* d_in, const int* in_sizes, int n_in,
                              void* d_out, int out_size, void* d_ws, size_t ws_size,
                              hipStream_t stream)
{
    const float* x    = (const float*)d_in[0];
    const int*   ei   = (const int*)d_in[1];
    const float* W0   = (const float*)d_in[2];
    const float* b0   = (const float*)d_in[3];
    const float* as0  = (const float*)d_in[4];
    const float* ad0  = (const float*)d_in[5];
    const float* W1   = (const float*)d_in[6];
    const float* b1   = (const float*)d_in[7];
    const float* as1  = (const float*)d_in[8];
    const float* ad1  = (const float*)d_in[9];
    const float* W2   = (const float*)d_in[10];
    const float* b2   = (const float*)d_in[11];
    const float* as2  = (const float*)d_in[12];
    const float* ad2  = (const float*)d_in[13];
    const float* sk0W = (const float*)d_in[14];
    const float* sk0b = (const float*)d_in[15];
    const float* sk2W = (const float*)d_in[16];
    const float* sk2b = (const float*)d_in[17];
    const float* jkW  = (const float*)d_in[18];
    const float* jkb  = (const float*)d_in[19];
    float* out = (float*)d_out;

    float* ws = (float*)d_ws;
    size_t off = 0;
    float* s_xh  = ws + off; off += (size_t)NN * 128;   // xh out (bf16 used as u16)
    float* s_r0  = ws + off; off += (size_t)NN * 128;   // res0 f32; reused as res2
    float* s_als = ws + off; off += (size_t)NN * 4;
    float* s_ald = ws + off; off += (size_t)NN * 4;
    ushort* u_wq = (ushort*)(ws + off); off += (size_t)EP * 2;   // packed bf16 wq
    ushort* s_xhb = (ushort*)s_xh;                      // bf16 view
    // split-bf16 activations (hi/lo), consumed by downstream GEMMs
    ushort* u_x0h = (ushort*)(ws + off); off += (size_t)NN * 64;   // [NN][128] u16
    ushort* u_x0l = (ushort*)(ws + off); off += (size_t)NN * 64;
    ushort* u_x1h = (ushort*)(ws + off); off += (size_t)NN * 64;
    ushort* u_x1l = (ushort*)(ws + off); off += (size_t)NN * 64;
    ushort* u_h2h = (ushort*)(ws + off); off += (size_t)NN * 32;   // [NN][64] u16
    ushort* u_h2l = (ushort*)(ws + off); off += (size_t)NN * 32;
    int* i_deg    = (int*)(ws + off); off += NN;
    int* i_rowptr = (int*)(ws + off); off += NN + 1;
    int* i_cursor = (int*)(ws + off); off += NN;
    int* i_csrsrc = (int*)(ws + off); off += EP;
    int* i_bsum   = (int*)(ws + off); off += NB;
    int* i_bsumx  = (int*)(ws + off); off += NB;
    off = (off + 3) & ~(size_t)3;     // 16B-align the bf16 weight tiles
    ushort* wt0h = (ushort*)(ws + off); off += 32768;   // 8*256*32 u16
    ushort* wt0l = (ushort*)(ws + off); off += 32768;
    ushort* wt1h = (ushort*)(ws + off); off += 8192;    // 4*128*32 u16
    ushort* wt1l = (ushort*)(ws + off); off += 8192;
    ushort* wt2h = (ushort*)(ws + off); off += 8192;    // 4*128*32 u16
    ushort* wt2l = (ushort*)(ws + off); off += 8192;
    ushort* wtjh = (ushort*)(ws + off); off += 10240;   // 10*64*32 u16
    ushort* wtjl = (ushort*)(ws + off); off += 10240;

    const int G128 = (NN + 127) / 128;    // 782 row blocks (128 rows each)
    const int GN = (NN + 255) / 256;      // node-thread blocks
    const int GS = (NN + 3) / 4;          // node-wave blocks
    constexpr int BIG = 1 << 30;

    // ======================= CSR build (shared by all 3 layers) ==========
    hipMemsetAsync(i_deg, 0, (size_t)NN * sizeof(int), stream);
    deg_kernel<<<(NE + 255) / 256, 256, 0, stream>>>(ei, i_deg);
    block_sum_kernel<<<NB, 256, 0, stream>>>(i_deg, i_bsum);
    scan_sums_kernel<<<1, 64, 0, stream>>>(i_bsum, i_bsumx, i_rowptr);
    scan_blocks_kernel<<<NB, 256, 0, stream>>>(i_deg, i_bsumx, i_rowptr, i_cursor);
    fill_kernel<<<(EP + 255) / 256, 256, 0, stream>>>(ei, i_cursor, i_csrsrc);

    // ======================= weight pre-tiling (split bf16) ==============
    pretile_kernel<<<256, 256, 0, stream>>>(W0, sk0W, 256, 128, 256, wt0h, wt0l);
    pretile_kernel<<<64,  256, 0, stream>>>(W1, nullptr, 128, 128, 128, wt1h, wt1l);
    pretile_kernel<<<64,  256, 0, stream>>>(W2, sk2W, 128, 64, 128, wt2h, wt2l);
    pretile_kernel<<<80,  256, 0, stream>>>(jkW, nullptr, 320, 64, 64, wtjh, wtjl);

    // ======= layer 0: fused [xh0 | res0] = x @ [W0 | sk0W] (K=256, N=256)
    //         B too big for resident-LDS: double-buffered (RESB=false)
    gemm_mfma<256, 256, 256, 256, 128, 128, 4, 32, 128, false, true, false, 2>
        <<<G128, 256, 0, stream>>>(
        x, nullptr, nullptr, nullptr, nullptr, nullptr, 256, 0, 0,
        wt0h, wt0l, sk0b,
        s_xhb, s_r0, 128, 128, s_als, s_ald, as0, ad0, NN);
    attn_weights_kernel<4><<<GN, 256, 0, stream>>>(
        i_rowptr, i_csrsrc, s_als, s_ald, u_wq, NN);
    spmm_kernel<4, 32, true, false><<<GS, 256, 0, stream>>>(
        i_rowptr, i_csrsrc, s_xhb, u_wq, b0, s_r0, nullptr, nullptr,
        u_x0h, u_x0l, NN);

    // ======= layer 1: xh1 = x0 @ W1 (K=128, N=128; resident-B, barrier-free)
    gemm_mfma<128, 128, 128, 128, 128, BIG, 4, 32, 128, true, true, true, 3>
        <<<G128, 256, 0, stream>>>(
        u_x0h, u_x0l, nullptr, nullptr, nullptr, nullptr, 128, 0, 0,
        wt1h, wt1l, nullptr,
        s_xhb, nullptr, 128, 0, s_als, s_ald, as1, ad1, NN);
    attn_weights_kernel<4><<<GN, 256, 0, stream>>>(
        i_rowptr, i_csrsrc, s_als, s_ald, u_wq, NN);
    spmm_kernel<4, 32, true, true><<<GS, 256, 0, stream>>>(
        i_rowptr, i_csrsrc, s_xhb, u_wq, b1, nullptr, u_x0h, u_x0l,
        u_x1h, u_x1l, NN);

    // ======= layer 2: fused [xh2 | res2] = x1 @ [W2 | sk2W] (resident-B)
    gemm_mfma<128, 128, 128, 128, 64, 64, 1, 64, 64, true, true, true, 3>
        <<<G128, 256, 0, stream>>>(
        u_x1h, u_x1l, nullptr, nullptr, nullptr, nullptr, 128, 0, 0,
        wt2h, wt2l, sk2b,
        s_xhb, s_r0, 64, 64, s_als, s_ald, as2, ad2, NN);
    attn_weights_kernel<1><<<GN, 256, 0, stream>>>(
        i_rowptr, i_csrsrc, s_als, s_ald, u_wq, NN);
    spmm_kernel<1, 64, false, false><<<GS, 256, 0, stream>>>(
        i_rowptr, i_csrsrc, s_xhb, u_wq, b2, s_r0, nullptr, nullptr,
        u_h2h, u_h2l, NN);

    // ======= JumpingKnowledge: out = [x0|x1|h2] @ jkW + jkb (resident-B,
    //         80 KB LDS, 10 k-tiles barrier-free)
    gemm_mfma<320, 64, 128, 256, 64, 0, 0, 16, 0, true, false, true, 3>
        <<<G128, 256, 0, stream>>>(
        u_x0h, u_x0l, u_x1h, u_x1l, u_h2h, u_h2l, 128, 128, 64,
        wtjh, wtjl, jkb,
        out, nullptr, 64, 0, nullptr, nullptr, nullptr, nullptr, NN);
}

// Round 14
// 530.674 us; speedup vs baseline: 1.0266x; 1.0266x over previous
//
#include <hip/hip_runtime.h>
#include <hip/hip_bf16.h>
#include <cstdint>

static constexpr int NN = 100000;     // nodes
static constexpr int NE = 800000;     // edges (without self loops)
static constexpr int EP = NE + NN;    // edges incl. self loops
static constexpr int NB = (NN + 255) / 256;  // scan blocks

typedef unsigned short ushort;
typedef __attribute__((ext_vector_type(8))) short short8;
typedef __attribute__((ext_vector_type(8))) ushort ushort8v;
typedef __attribute__((ext_vector_type(4))) float f32x4;

__device__ __forceinline__ float leaky(float x) { return x > 0.f ? x : 0.2f * x; }

// float -> bf16 bits (RNE)
__device__ __forceinline__ ushort f2bf(float f) {
    unsigned int u = __float_as_uint(f);
    u += 0x7fffu + ((u >> 16) & 1u);
    return (ushort)(u >> 16);
}
__device__ __forceinline__ float bf2f(ushort h) {
    return __uint_as_float(((unsigned int)h) << 16);
}

// async global->LDS 16B copy: per-lane global src; LDS dest = base + lane*16.
__device__ __forceinline__ void gload16(const void* g, void* l) {
    __builtin_amdgcn_global_load_lds((__attribute__((address_space(1))) void*)g,
                                     (__attribute__((address_space(3))) void*)l,
                                     16, 0, 0);
}

// T4 counted-vmcnt barrier: B-stage (oldest VMEM ops) must be complete;
// the N newest (A register prefetch) stay in flight across the barrier.
template<int N>
__device__ __forceinline__ void waitbarN() {
    if constexpr (N == 4) asm volatile("s_waitcnt vmcnt(4)" ::: "memory");
    else                  asm volatile("s_waitcnt vmcnt(2)" ::: "memory");
    __builtin_amdgcn_s_barrier();
    __builtin_amdgcn_sched_barrier(0);
}

// ---------------------------------------------------------------------------
// Weight pre-tiling: W (virtual concat [Wa | Wb], K x NT, row-major) ->
//   Whi/Wlo: [K/32][NT][32] bf16 (hi + lo split) — the MFMA B-frag layout.
// ---------------------------------------------------------------------------
__global__ void pretile_kernel(const float* __restrict__ Wa, const float* __restrict__ Wb,
                               int K, int CS, int NT,
                               ushort* __restrict__ Whi, ushort* __restrict__ Wlo)
{
    int idx = blockIdx.x * 256 + threadIdx.x;
    if (idx >= K * NT) return;
    int k = idx / NT, c = idx - k * NT;
    float v = (c < CS) ? Wa[(size_t)k * CS + c] : Wb[(size_t)k * (NT - CS) + (c - CS)];
    ushort h = f2bf(v);
    ushort l = f2bf(v - bf2f(h));
    size_t o = ((size_t)(k >> 5) * NT + c) * 32 + (k & 31);
    Whi[o] = h; Wlo[o] = l;
}

// ---------------------------------------------------------------------------
// Split-bf16 MFMA GEMM (3-pass hi/lo, ~fp32 accuracy), "wave-private rows"
// + T4 counted-vmcnt pipeline.
//   MF = 16-row fragments per wave (wave tile = MF*16 rows x NTOT cols).
//   Block covers 128 rows -> WAVES = 128/(MF*16), TPB = WAVES*64.
//   MF=2: 4 waves/256 thr (R12-proven).  MF=1: 8 waves/512 thr — halves
//   acc VGPRs (64) to unlock 4 waves/SIMD occupancy for L0.
//   Y1BF: store Y1 (xh consumed by gather-SpMM) as bf16.
// ---------------------------------------------------------------------------
template<int KTOT, int NTOT, int MF, int K1, int K2, int CSPLIT, int BIAS_OFF,
         int AHH, int ACC, int ATTN, bool ASPLIT, bool Y1BF, int MINW>
__global__ __launch_bounds__((128 / (MF * 16)) * 64, MINW)
void gemm_mfma(const void* __restrict__ X1, const void* __restrict__ X1b,
               const void* __restrict__ X2, const void* __restrict__ X2b,
               const void* __restrict__ X3, const void* __restrict__ X3b,
               int ldx1, int ldx2, int ldx3,
               const ushort* __restrict__ Wthi, const ushort* __restrict__ Wtlo,
               const float* __restrict__ bias,
               void* __restrict__ Y1, float* __restrict__ Y2, int ldy1, int ldy2,
               float* __restrict__ als, float* __restrict__ ald,
               const float* __restrict__ a_src, const float* __restrict__ a_dst,
               int n)
{
    constexpr int NKT = KTOT / 32;
    constexpr int NF  = NTOT / 16;            // col frags per wave (full N)
    constexpr int TPB = (128 / (MF * 16)) * 64;
    constexpr int AINFLIGHT = 2 * MF;         // A-loads left in flight at bar

    __shared__ ushort Bh[2][NTOT * 32], Bl[2][NTOT * 32];

    const int t = threadIdx.x, l = t & 63, w = t >> 6;
    const int lc = l & 15, lq = l >> 4;
    const int wrow = blockIdx.x * 128 + w * (MF * 16);  // wave's private rows

    f32x4 acc[MF][NF];
#pragma unroll
    for (int mf = 0; mf < MF; ++mf)
#pragma unroll
        for (int nf = 0; nf < NF; ++nf)
            acc[mf][nf] = (f32x4){0.f, 0.f, 0.f, 0.f};

    int arow[MF], rcl[MF];
#pragma unroll
    for (int mf = 0; mf < MF; ++mf) {
        arow[mf] = wrow + mf * 16 + lc;
        rcl[mf]  = arow[mf] < n ? arow[mf] : (n - 1);   // clamp: uniform issue
    }

    // A register double-buffer (named slots; static under full unroll)
    short8 A0h[MF], A0l[MF], A1h[MF], A1l[MF];   // split path
    float4 F0[MF][2], F1[MF][2];                 // f32 path (raw)

    auto loadA = [&](int kt, short8 (&dh)[MF], short8 (&dl)[MF], float4 (&df)[MF][2]) {
        const int k0 = kt * 32;
        const void* xp; const void* xq; int ldx, koff;
        if (k0 < K1)      { xp = X1; xq = X1b; ldx = ldx1; koff = k0; }
        else if (k0 < K2) { xp = X2; xq = X2b; ldx = ldx2; koff = k0 - K1; }
        else              { xp = X3; xq = X3b; ldx = ldx3; koff = k0 - K2; }
        if constexpr (ASPLIT) {
            const ushort* ph = (const ushort*)xp;
            const ushort* pl = (const ushort*)xq;
#pragma unroll
            for (int mf = 0; mf < MF; ++mf) {
                size_t o = (size_t)rcl[mf] * ldx + koff + lq * 8;
                dh[mf] = *(const short8*)&ph[o];
                dl[mf] = *(const short8*)&pl[o];
            }
        } else {
            const float* pf = (const float*)xp;
#pragma unroll
            for (int mf = 0; mf < MF; ++mf) {
                size_t o = (size_t)rcl[mf] * ldx + koff + lq * 8;
                df[mf][0] = *(const float4*)&pf[o];
                df[mf][1] = *(const float4*)&pf[o + 4];
            }
        }
    };

    auto stageB = [&](int kt, int buf) {
        constexpr int UN = NTOT * 4;           // 16B units per (hi or lo) tile
#pragma unroll
        for (int s = 0; s < UN / TPB; ++s) {
            int unit = s * TPB + t;            // = kq*NTOT + col (linear)
            int col  = unit & (NTOT - 1);
            int kq   = unit / NTOT;
            size_t go = ((size_t)kt * NTOT + col) * 32 + kq * 8;
            gload16(&Wthi[go], &Bh[buf][unit * 8]);
            gload16(&Wtlo[go], &Bl[buf][unit * 8]);
        }
    };

    // prologue: stage oldest, then A prefetch, counted wait
    stageB(0, 0);
    __builtin_amdgcn_sched_barrier(0);         // pin issue order: B before A
    loadA(0, A0h, A0l, F0);
    waitbarN<AINFLIGHT>();                     // B(0) in LDS; A(0) in flight

#pragma unroll
    for (int kt = 0; kt < NKT; ++kt) {
        if (kt + 1 < NKT) {
            stageB(kt + 1, (kt + 1) & 1);      // oldest VMEM this tile
            __builtin_amdgcn_sched_barrier(0); // keep A-loads newest
            if (((kt + 1) & 1) == 0) loadA(kt + 1, A0h, A0l, F0);
            else                     loadA(kt + 1, A1h, A1l, F1);
        }

        short8 ah[MF], al[MF];
        if constexpr (ASPLIT) {
            if ((kt & 1) == 0) {
#pragma unroll
                for (int mf = 0; mf < MF; ++mf) { ah[mf] = A0h[mf]; al[mf] = A0l[mf]; }
            } else {
#pragma unroll
                for (int mf = 0; mf < MF; ++mf) { ah[mf] = A1h[mf]; al[mf] = A1l[mf]; }
            }
        } else {
            const auto& Fc = (kt & 1) ? F1 : F0;
#pragma unroll
            for (int mf = 0; mf < MF; ++mf) {
                short8 h8, l8;
#pragma unroll
                for (int e = 0; e < 8; ++e) {
                    float f = (e < 4) ? (&Fc[mf][0].x)[e] : (&Fc[mf][1].x)[e - 4];
                    ushort hh = f2bf(f);
                    h8[e] = (short)hh;
                    l8[e] = (short)f2bf(f - bf2f(hh));
                }
                ah[mf] = h8; al[mf] = l8;
            }
        }

        const int cb = kt & 1;
#pragma unroll
        for (int nf = 0; nf < NF; ++nf) {
            int bslot = lq * NTOT + nf * 16 + lc;
            short8 bh = *(const short8*)&Bh[cb][bslot * 8];
            short8 bl = *(const short8*)&Bl[cb][bslot * 8];
#pragma unroll
            for (int mf = 0; mf < MF; ++mf) {
                acc[mf][nf] = __builtin_amdgcn_mfma_f32_16x16x32_bf16(ah[mf], bh, acc[mf][nf], 0, 0, 0);
                acc[mf][nf] = __builtin_amdgcn_mfma_f32_16x16x32_bf16(ah[mf], bl, acc[mf][nf], 0, 0, 0);
                acc[mf][nf] = __builtin_amdgcn_mfma_f32_16x16x32_bf16(al[mf], bh, acc[mf][nf], 0, 0, 0);
            }
        }
        if (kt + 1 < NKT) waitbarN<AINFLIGHT>();  // B(t+1) landed; A(t+1) flying
    }

    // ---- attention-logit epilogue (f32 accumulator — full precision) ----
    if constexpr (AHH > 0) {
        constexpr int FPH = ACC / 16;     // frags per head
        constexpr int NG  = ATTN / ACC;   // heads (all live in this wave)
#pragma unroll
        for (int g = 0; g < NG; ++g) {
#pragma unroll
            for (int mf = 0; mf < MF; ++mf) {
                float ps[4] = {0.f, 0.f, 0.f, 0.f};
                float pd[4] = {0.f, 0.f, 0.f, 0.f};
#pragma unroll
                for (int j = 0; j < FPH; ++j) {
                    int col = g * ACC + j * 16 + lc;
                    float av = a_src[col], dv = a_dst[col];
#pragma unroll
                    for (int r = 0; r < 4; ++r) {
                        ps[r] = fmaf(acc[mf][g * FPH + j][r], av, ps[r]);
                        pd[r] = fmaf(acc[mf][g * FPH + j][r], dv, pd[r]);
                    }
                }
#pragma unroll
                for (int off = 1; off < 16; off <<= 1)
#pragma unroll
                    for (int r = 0; r < 4; ++r) {
                        ps[r] += __shfl_xor(ps[r], off);
                        pd[r] += __shfl_xor(pd[r], off);
                    }
                if (lc == 0) {
#pragma unroll
                    for (int r = 0; r < 4; ++r) {
                        int row = wrow + mf * 16 + lq * 4 + r;
                        if (row < n) {
                            als[(size_t)row * AHH + g] = ps[r];
                            ald[(size_t)row * AHH + g] = pd[r];
                        }
                    }
                }
            }
        }
    }

    // ---- store (+ bias for cols >= BIAS_OFF); Y1 optionally bf16 ----
#pragma unroll
    for (int mf = 0; mf < MF; ++mf) {
        int rb4 = wrow + mf * 16 + lq * 4;
#pragma unroll
        for (int nf = 0; nf < NF; ++nf) {
            int col = nf * 16 + lc;
            float bv = 0.f;
            if constexpr (BIAS_OFF < NTOT) {
                if (col >= BIAS_OFF) bv = bias[col - BIAS_OFF];
            }
#pragma unroll
            for (int r = 0; r < 4; ++r) {
                int row = rb4 + r;
                if (row < n) {
                    float v = acc[mf][nf][r] + bv;
                    if (col < CSPLIT) {
                        if constexpr (Y1BF)
                            ((ushort*)Y1)[(size_t)row * ldy1 + col] = f2bf(v);
                        else
                            ((float*)Y1)[(size_t)row * ldy1 + col] = v;
                    } else {
                        Y2[(size_t)row * ldy2 + (col - CSPLIT)] = v;
                    }
                }
            }
        }
    }
}

// ---------------------------------------------------------------------------
// CSR build: histogram -> block sums -> scan sums -> per-block scan -> fill
// ---------------------------------------------------------------------------
__global__ void deg_kernel(const int* __restrict__ ei, int* __restrict__ deg)
{
    int t = blockIdx.x * blockDim.x + threadIdx.x;
    if (t < NE) atomicAdd(&deg[ei[NE + t]], 1);   // dst of edge t
}

__global__ void block_sum_kernel(const int* __restrict__ deg, int* __restrict__ bsum)
{
    int node = blockIdx.x * 256 + threadIdx.x;
    int v = (node < NN) ? deg[node] + 1 : 0;      // +1 = self loop
#pragma unroll
    for (int off = 32; off > 0; off >>= 1) v += __shfl_down(v, off);
    __shared__ int sh[4];
    if ((threadIdx.x & 63) == 0) sh[threadIdx.x >> 6] = v;
    __syncthreads();
    if (threadIdx.x == 0) bsum[blockIdx.x] = sh[0] + sh[1] + sh[2] + sh[3];
}

__global__ void scan_sums_kernel(const int* __restrict__ bsum, int* __restrict__ bsumx,
                                 int* __restrict__ rowptr)
{
    if (threadIdx.x == 0) {
        int run = 0;
        for (int i = 0; i < NB; ++i) { bsumx[i] = run; run += bsum[i]; }
        rowptr[NN] = run;    // == EP
    }
}

__global__ void scan_blocks_kernel(const int* __restrict__ deg, const int* __restrict__ bsumx,
                                   int* __restrict__ rowptr, int* __restrict__ cursor)
{
    __shared__ int sh[256];
    int node = blockIdx.x * 256 + threadIdx.x;
    int v = (node < NN) ? deg[node] + 1 : 0;
    sh[threadIdx.x] = v;
    __syncthreads();
#pragma unroll
    for (int off = 1; off < 256; off <<= 1) {
        int tv = (threadIdx.x >= off) ? sh[threadIdx.x - off] : 0;
        __syncthreads();
        sh[threadIdx.x] += tv;
        __syncthreads();
    }
    if (node < NN) {
        int excl = bsumx[blockIdx.x] + sh[threadIdx.x] - v;
        rowptr[node] = excl;
        cursor[node] = excl;
    }
}

__global__ void fill_kernel(const int* __restrict__ ei, int* __restrict__ cursor,
                            int* __restrict__ csr_src)
{
    int t = blockIdx.x * blockDim.x + threadIdx.x;
    if (t >= EP) return;
    int s, d;
    if (t < NE) { s = ei[t]; d = ei[NE + t]; }
    else        { s = d = t - NE; }
    int pos = atomicAdd(&cursor[d], 1);
    csr_src[pos] = s;
}

// ---------------------------------------------------------------------------
// Softmax stats + normalized edge weights (packed bf16). ONE THREAD PER NODE.
// ---------------------------------------------------------------------------
template<int HH>
__global__ __launch_bounds__(256)
void attn_weights_kernel(const int* __restrict__ rowptr, const int* __restrict__ csr_src,
                         const float* __restrict__ als, const float* __restrict__ ald,
                         ushort* __restrict__ wq, int n)
{
    int node = blockIdx.x * 256 + threadIdx.x;
    if (node >= n) return;
    const int e0 = rowptr[node], e1 = rowptr[node + 1];
    float aldv[HH], m[HH], d[HH];
#pragma unroll
    for (int h = 0; h < HH; ++h) { m[h] = -1e30f; d[h] = 0.f; }
    if constexpr (HH == 4) {
        float4 a = *(const float4*)&ald[(size_t)node * 4];
        aldv[0] = a.x; aldv[1] = a.y; aldv[2] = a.z; aldv[3] = a.w;
    } else {
        aldv[0] = ald[node];
    }
    for (int e = e0; e < e1; ++e) {
        int s = csr_src[e];
        float av[HH];
        if constexpr (HH == 4) {
            float4 a = *(const float4*)&als[(size_t)s * 4];
            av[0] = a.x; av[1] = a.y; av[2] = a.z; av[3] = a.w;
        } else {
            av[0] = als[s];
        }
#pragma unroll
        for (int h = 0; h < HH; ++h) {
            float sc = leaky(av[h] + aldv[h]);
            float nm = fmaxf(m[h], sc);
            d[h] = d[h] * __expf(m[h] - nm) + __expf(sc - nm);
            m[h] = nm;
        }
    }
#pragma unroll
    for (int h = 0; h < HH; ++h) d[h] = 1.f / d[h];
    for (int e = e0; e < e1; ++e) {
        int s = csr_src[e];
        float av[HH];
        if constexpr (HH == 4) {
            float4 a = *(const float4*)&als[(size_t)s * 4];
            av[0] = a.x; av[1] = a.y; av[2] = a.z; av[3] = a.w;
        } else {
            av[0] = als[s];
        }
        if constexpr (HH == 4) {
            uint2 o;
            unsigned int w0 = f2bf(__expf(leaky(av[0] + aldv[0]) - m[0]) * d[0]);
            unsigned int w1 = f2bf(__expf(leaky(av[1] + aldv[1]) - m[1]) * d[1]);
            unsigned int w2 = f2bf(__expf(leaky(av[2] + aldv[2]) - m[2]) * d[2]);
            unsigned int w3 = f2bf(__expf(leaky(av[3] + aldv[3]) - m[3]) * d[3]);
            o.x = w0 | (w1 << 16);
            o.y = w2 | (w3 << 16);
            *(uint2*)&wq[(size_t)e * 4] = o;
        } else {
            wq[e] = f2bf(__expf(leaky(av[0] + aldv[0]) - m[0]) * d[0]);
        }
    }
}

// ---------------------------------------------------------------------------
// Weighted gather-SpMM + fused epilogue. ONE WAVE PER NODE, lane = channel
// pair. xh gathered as bf16; wq read as bf16. 4-edge unroll for load ILP.
// Output written as pre-split hi/lo bf16. Residual f32 or split (RESSPLIT).
// ---------------------------------------------------------------------------
template<int HH, int CC, bool DOELU, bool RESSPLIT>
__global__ __launch_bounds__(256)
void spmm_kernel(const int* __restrict__ rowptr, const int* __restrict__ csr_src,
                 const ushort* __restrict__ xh, const ushort* __restrict__ wq,
                 const float* __restrict__ b,
                 const float* __restrict__ resf,
                 const ushort* __restrict__ resh, const ushort* __restrict__ resl,
                 ushort* __restrict__ outh, ushort* __restrict__ outl, int n)
{
    constexpr int HCL = HH * CC;
    constexpr int CPL = HCL / 64;                 // channels per lane (2 or 1)
    const int l = threadIdx.x & 63;
    const int node = blockIdx.x * 4 + (threadIdx.x >> 6);
    if (node >= n) return;
    const int c = l * CPL;
    const int h = c / CC;
    const int e0 = rowptr[node], e1 = rowptr[node + 1];

    float a0[CPL], a1[CPL];
#pragma unroll
    for (int j = 0; j < CPL; ++j) { a0[j] = 0.f; a1[j] = 0.f; }

    auto gather = [&](int e, float* accv) {
        int s = csr_src[e];
        float w0 = bf2f(wq[(size_t)e * HH + h]);
        if constexpr (CPL == 2) {
            unsigned int uv = *(const unsigned int*)&xh[(size_t)s * HCL + c];
            accv[0] = fmaf(w0, bf2f((ushort)(uv & 0xffffu)), accv[0]);
            accv[1] = fmaf(w0, bf2f((ushort)(uv >> 16)), accv[1]);
        } else {
            accv[0] = fmaf(w0, bf2f(xh[(size_t)s * HCL + c]), accv[0]);
        }
    };

    int e = e0;
    for (; e + 3 < e1; e += 4) {
        gather(e, a0); gather(e + 1, a1);
        gather(e + 2, a0); gather(e + 3, a1);
    }
    for (; e < e1; ++e) gather(e, a0);

#pragma unroll
    for (int j = 0; j < CPL; ++j) {
        size_t idx = (size_t)node * HCL + c + j;
        float rv;
        if constexpr (RESSPLIT) rv = bf2f(resh[idx]) + bf2f(resl[idx]);
        else                    rv = resf[idx];
        float v = a0[j] + a1[j] + b[c + j] + rv;
        if (DOELU) v = v > 0.f ? v : (__expf(v) - 1.f);
        ushort hh = f2bf(v);
        outh[idx] = hh;
        outl[idx] = f2bf(v - bf2f(hh));
    }
}

// ---------------------------------------------------------------------------
extern "C" void kernel_launch(void* const* d_in, const int* in_sizes, int n_in,
                              void* d_out, int out_size, void* d_ws, size_t ws_size,
                              hipStream_t stream)
{
    const float* x    = (const float*)d_in[0];
    const int*   ei   = (const int*)d_in[1];
    const float* W0   = (const float*)d_in[2];
    const float* b0   = (const float*)d_in[3];
    const float* as0  = (const float*)d_in[4];
    const float* ad0  = (const float*)d_in[5];
    const float* W1   = (const float*)d_in[6];
    const float* b1   = (const float*)d_in[7];
    const float* as1  = (const float*)d_in[8];
    const float* ad1  = (const float*)d_in[9];
    const float* W2   = (const float*)d_in[10];
    const float* b2   = (const float*)d_in[11];
    const float* as2  = (const float*)d_in[12];
    const float* ad2  = (const float*)d_in[13];
    const float* sk0W = (const float*)d_in[14];
    const float* sk0b = (const float*)d_in[15];
    const float* sk2W = (const float*)d_in[16];
    const float* sk2b = (const float*)d_in[17];
    const float* jkW  = (const float*)d_in[18];
    const float* jkb  = (const float*)d_in[19];
    float* out = (float*)d_out;

    float* ws = (float*)d_ws;
    size_t off = 0;
    float* s_xh  = ws + off; off += (size_t)NN * 128;   // xh out (bf16 used as u16)
    float* s_r0  = ws + off; off += (size_t)NN * 128;   // res0 f32; reused as res2
    float* s_als = ws + off; off += (size_t)NN * 4;
    float* s_ald = ws + off; off += (size_t)NN * 4;
    ushort* u_wq = (ushort*)(ws + off); off += (size_t)EP * 2;   // packed bf16 wq
    ushort* s_xhb = (ushort*)s_xh;                      // bf16 view
    // split-bf16 activations (hi/lo), consumed by downstream GEMMs
    ushort* u_x0h = (ushort*)(ws + off); off += (size_t)NN * 64;   // [NN][128] u16
    ushort* u_x0l = (ushort*)(ws + off); off += (size_t)NN * 64;
    ushort* u_x1h = (ushort*)(ws + off); off += (size_t)NN * 64;
    ushort* u_x1l = (ushort*)(ws + off); off += (size_t)NN * 64;
    ushort* u_h2h = (ushort*)(ws + off); off += (size_t)NN * 32;   // [NN][64] u16
    ushort* u_h2l = (ushort*)(ws + off); off += (size_t)NN * 32;
    int* i_deg    = (int*)(ws + off); off += NN;
    int* i_rowptr = (int*)(ws + off); off += NN + 1;
    int* i_cursor = (int*)(ws + off); off += NN;
    int* i_csrsrc = (int*)(ws + off); off += EP;
    int* i_bsum   = (int*)(ws + off); off += NB;
    int* i_bsumx  = (int*)(ws + off); off += NB;
    off = (off + 3) & ~(size_t)3;     // 16B-align the bf16 weight tiles
    ushort* wt0h = (ushort*)(ws + off); off += 32768;   // 8*256*32 u16
    ushort* wt0l = (ushort*)(ws + off); off += 32768;
    ushort* wt1h = (ushort*)(ws + off); off += 8192;    // 4*128*32 u16
    ushort* wt1l = (ushort*)(ws + off); off += 8192;
    ushort* wt2h = (ushort*)(ws + off); off += 8192;    // 4*128*32 u16
    ushort* wt2l = (ushort*)(ws + off); off += 8192;
    ushort* wtjh = (ushort*)(ws + off); off += 10240;   // 10*64*32 u16
    ushort* wtjl = (ushort*)(ws + off); off += 10240;

    const int G128 = (NN + 127) / 128;    // 782 row blocks (128 rows each)
    const int GN = (NN + 255) / 256;      // node-thread blocks
    const int GS = (NN + 3) / 4;          // node-wave blocks
    constexpr int BIG = 1 << 30;

    // ======================= CSR build (shared by all 3 layers) ==========
    hipMemsetAsync(i_deg, 0, (size_t)NN * sizeof(int), stream);
    deg_kernel<<<(NE + 255) / 256, 256, 0, stream>>>(ei, i_deg);
    block_sum_kernel<<<NB, 256, 0, stream>>>(i_deg, i_bsum);
    scan_sums_kernel<<<1, 64, 0, stream>>>(i_bsum, i_bsumx, i_rowptr);
    scan_blocks_kernel<<<NB, 256, 0, stream>>>(i_deg, i_bsumx, i_rowptr, i_cursor);
    fill_kernel<<<(EP + 255) / 256, 256, 0, stream>>>(ei, i_cursor, i_csrsrc);

    // ======================= weight pre-tiling (split bf16) ==============
    pretile_kernel<<<256, 256, 0, stream>>>(W0, sk0W, 256, 128, 256, wt0h, wt0l);
    pretile_kernel<<<64,  256, 0, stream>>>(W1, nullptr, 128, 128, 128, wt1h, wt1l);
    pretile_kernel<<<64,  256, 0, stream>>>(W2, sk2W, 128, 64, 128, wt2h, wt2l);
    pretile_kernel<<<80,  256, 0, stream>>>(jkW, nullptr, 320, 64, 64, wtjh, wtjl);

    // ======= layer 0: fused [xh0 | res0] = x @ [W0 | sk0W] (K=256, N=256)
    //         MF=1: 8 waves x 16 rows, 512 thr, acc=64 VGPR -> 4 waves/SIMD
    gemm_mfma<256, 256, 1, 256, 256, 128, 128, 4, 32, 128, false, true, 4>
        <<<G128, 512, 0, stream>>>(
        x, nullptr, nullptr, nullptr, nullptr, nullptr, 256, 0, 0,
        wt0h, wt0l, sk0b,
        s_xhb, s_r0, 128, 128, s_als, s_ald, as0, ad0, NN);
    attn_weights_kernel<4><<<GN, 256, 0, stream>>>(
        i_rowptr, i_csrsrc, s_als, s_ald, u_wq, NN);
    spmm_kernel<4, 32, true, false><<<GS, 256, 0, stream>>>(
        i_rowptr, i_csrsrc, s_xhb, u_wq, b0, s_r0, nullptr, nullptr,
        u_x0h, u_x0l, NN);

    // ======= layer 1: xh1 = x0 @ W1 (K=128, N=128; R12-proven MF=2 config)
    gemm_mfma<128, 128, 2, 128, 128, 128, BIG, 4, 32, 128, true, true, 3>
        <<<G128, 256, 0, stream>>>(
        u_x0h, u_x0l, nullptr, nullptr, nullptr, nullptr, 128, 0, 0,
        wt1h, wt1l, nullptr,
        s_xhb, nullptr, 128, 0, s_als, s_ald, as1, ad1, NN);
    attn_weights_kernel<4><<<GN, 256, 0, stream>>>(
        i_rowptr, i_csrsrc, s_als, s_ald, u_wq, NN);
    spmm_kernel<4, 32, true, true><<<GS, 256, 0, stream>>>(
        i_rowptr, i_csrsrc, s_xhb, u_wq, b1, nullptr, u_x0h, u_x0l,
        u_x1h, u_x1l, NN);

    // ======= layer 2: fused [xh2 | res2] = x1 @ [W2 | sk2W] (K=128, N=128)
    gemm_mfma<128, 128, 2, 128, 128, 64, 64, 1, 64, 64, true, true, 3>
        <<<G128, 256, 0, stream>>>(
        u_x1h, u_x1l, nullptr, nullptr, nullptr, nullptr, 128, 0, 0,
        wt2h, wt2l, sk2b,
        s_xhb, s_r0, 64, 64, s_als, s_ald, as2, ad2, NN);
    attn_weights_kernel<1><<<GN, 256, 0, stream>>>(
        i_rowptr, i_csrsrc, s_als, s_ald, u_wq, NN);
    spmm_kernel<1, 64, false, false><<<GS, 256, 0, stream>>>(
        i_rowptr, i_csrsrc, s_xhb, u_wq, b2, s_r0, nullptr, nullptr,
        u_h2h, u_h2l, NN);

    // ======= JumpingKnowledge: out = [x0|x1|h2] @ jkW + jkb (K=320, N=64)
    gemm_mfma<320, 64, 2, 128, 256, 64, 0, 0, 16, 0, true, false, 3>
        <<<G128, 256, 0, stream>>>(
        u_x0h, u_x0l, u_x1h, u_x1l, u_h2h, u_h2l, 128, 128, 64,
        wtjh, wtjl, jkb,
        out, nullptr, 64, 0, nullptr, nullptr, nullptr, nullptr, NN);
}

// Round 15
// 525.203 us; speedup vs baseline: 1.0373x; 1.0104x over previous
//
#include <hip/hip_runtime.h>
#include <hip/hip_bf16.h>
#include <cstdint>

static constexpr int NN = 100000;     // nodes
static constexpr int NE = 800000;     // edges (without self loops)
static constexpr int EP = NE + NN;    // edges incl. self loops
static constexpr int NB = (NN + 255) / 256;  // scan blocks

typedef unsigned short ushort;
typedef __attribute__((ext_vector_type(8))) short short8;
typedef __attribute__((ext_vector_type(8))) ushort ushort8v;
typedef __attribute__((ext_vector_type(4))) float f32x4;

__device__ __forceinline__ float leaky(float x) { return x > 0.f ? x : 0.2f * x; }

// float -> bf16 bits (RNE)
__device__ __forceinline__ ushort f2bf(float f) {
    unsigned int u = __float_as_uint(f);
    u += 0x7fffu + ((u >> 16) & 1u);
    return (ushort)(u >> 16);
}
__device__ __forceinline__ float bf2f(ushort h) {
    return __uint_as_float(((unsigned int)h) << 16);
}

// async global->LDS 16B copy: per-lane global src; LDS dest = base + lane*16.
__device__ __forceinline__ void gload16(const void* g, void* l) {
    __builtin_amdgcn_global_load_lds((__attribute__((address_space(1))) void*)g,
                                     (__attribute__((address_space(3))) void*)l,
                                     16, 0, 0);
}

// T4 counted-vmcnt barrier: B-stage (oldest VMEM ops) must be complete;
// the N newest (A register prefetch) stay in flight across the barrier.
template<int N>
__device__ __forceinline__ void waitbarN() {
    if constexpr (N == 4) asm volatile("s_waitcnt vmcnt(4)" ::: "memory");
    else                  asm volatile("s_waitcnt vmcnt(2)" ::: "memory");
    __builtin_amdgcn_s_barrier();
    __builtin_amdgcn_sched_barrier(0);
}

// ---------------------------------------------------------------------------
// Weight pre-tiling: W (virtual concat [Wa | Wb], K x NT, row-major) ->
//   Whi/Wlo: [K/32][NT][32] bf16 (hi + lo split) — the MFMA B-frag layout.
// ---------------------------------------------------------------------------
__global__ void pretile_kernel(const float* __restrict__ Wa, const float* __restrict__ Wb,
                               int K, int CS, int NT,
                               ushort* __restrict__ Whi, ushort* __restrict__ Wlo)
{
    int idx = blockIdx.x * 256 + threadIdx.x;
    if (idx >= K * NT) return;
    int k = idx / NT, c = idx - k * NT;
    float v = (c < CS) ? Wa[(size_t)k * CS + c] : Wb[(size_t)k * (NT - CS) + (c - CS)];
    ushort h = f2bf(v);
    ushort l = f2bf(v - bf2f(h));
    size_t o = ((size_t)(k >> 5) * NT + c) * 32 + (k & 31);
    Whi[o] = h; Wlo[o] = l;
}

// ---------------------------------------------------------------------------
// Split-bf16 MFMA GEMM (3-pass hi/lo, ~fp32 accuracy), "wave-private rows"
// + T4 counted-vmcnt pipeline.
//   MF = 16-row fragments per wave; block covers 128 rows.
//   MF=2: 4 waves/256 thr.  MF=1: 8 waves/512 thr (L0: acc=64 VGPR).
//   Y1BF / Y2BF: store Y1 / Y2 as bf16 (halves downstream traffic).
// ---------------------------------------------------------------------------
template<int KTOT, int NTOT, int MF, int K1, int K2, int CSPLIT, int BIAS_OFF,
         int AHH, int ACC, int ATTN, bool ASPLIT, bool Y1BF, bool Y2BF, int MINW>
__global__ __launch_bounds__((128 / (MF * 16)) * 64, MINW)
void gemm_mfma(const void* __restrict__ X1, const void* __restrict__ X1b,
               const void* __restrict__ X2, const void* __restrict__ X2b,
               const void* __restrict__ X3, const void* __restrict__ X3b,
               int ldx1, int ldx2, int ldx3,
               const ushort* __restrict__ Wthi, const ushort* __restrict__ Wtlo,
               const float* __restrict__ bias,
               void* __restrict__ Y1, void* __restrict__ Y2, int ldy1, int ldy2,
               float* __restrict__ als, float* __restrict__ ald,
               const float* __restrict__ a_src, const float* __restrict__ a_dst,
               int n)
{
    constexpr int NKT = KTOT / 32;
    constexpr int NF  = NTOT / 16;            // col frags per wave (full N)
    constexpr int TPB = (128 / (MF * 16)) * 64;
    constexpr int AINFLIGHT = 2 * MF;         // A-loads left in flight at bar

    __shared__ ushort Bh[2][NTOT * 32], Bl[2][NTOT * 32];

    const int t = threadIdx.x, l = t & 63, w = t >> 6;
    const int lc = l & 15, lq = l >> 4;
    const int wrow = blockIdx.x * 128 + w * (MF * 16);  // wave's private rows

    f32x4 acc[MF][NF];
#pragma unroll
    for (int mf = 0; mf < MF; ++mf)
#pragma unroll
        for (int nf = 0; nf < NF; ++nf)
            acc[mf][nf] = (f32x4){0.f, 0.f, 0.f, 0.f};

    int arow[MF], rcl[MF];
#pragma unroll
    for (int mf = 0; mf < MF; ++mf) {
        arow[mf] = wrow + mf * 16 + lc;
        rcl[mf]  = arow[mf] < n ? arow[mf] : (n - 1);   // clamp: uniform issue
    }

    // A register double-buffer (named slots; static under full unroll)
    short8 A0h[MF], A0l[MF], A1h[MF], A1l[MF];   // split path
    float4 F0[MF][2], F1[MF][2];                 // f32 path (raw)

    auto loadA = [&](int kt, short8 (&dh)[MF], short8 (&dl)[MF], float4 (&df)[MF][2]) {
        const int k0 = kt * 32;
        const void* xp; const void* xq; int ldx, koff;
        if (k0 < K1)      { xp = X1; xq = X1b; ldx = ldx1; koff = k0; }
        else if (k0 < K2) { xp = X2; xq = X2b; ldx = ldx2; koff = k0 - K1; }
        else              { xp = X3; xq = X3b; ldx = ldx3; koff = k0 - K2; }
        if constexpr (ASPLIT) {
            const ushort* ph = (const ushort*)xp;
            const ushort* pl = (const ushort*)xq;
#pragma unroll
            for (int mf = 0; mf < MF; ++mf) {
                size_t o = (size_t)rcl[mf] * ldx + koff + lq * 8;
                dh[mf] = *(const short8*)&ph[o];
                dl[mf] = *(const short8*)&pl[o];
            }
        } else {
            const float* pf = (const float*)xp;
#pragma unroll
            for (int mf = 0; mf < MF; ++mf) {
                size_t o = (size_t)rcl[mf] * ldx + koff + lq * 8;
                df[mf][0] = *(const float4*)&pf[o];
                df[mf][1] = *(const float4*)&pf[o + 4];
            }
        }
    };

    auto stageB = [&](int kt, int buf) {
        constexpr int UN = NTOT * 4;           // 16B units per (hi or lo) tile
#pragma unroll
        for (int s = 0; s < UN / TPB; ++s) {
            int unit = s * TPB + t;            // = kq*NTOT + col (linear)
            int col  = unit & (NTOT - 1);
            int kq   = unit / NTOT;
            size_t go = ((size_t)kt * NTOT + col) * 32 + kq * 8;
            gload16(&Wthi[go], &Bh[buf][unit * 8]);
            gload16(&Wtlo[go], &Bl[buf][unit * 8]);
        }
    };

    // prologue: stage oldest, then A prefetch, counted wait
    stageB(0, 0);
    __builtin_amdgcn_sched_barrier(0);         // pin issue order: B before A
    loadA(0, A0h, A0l, F0);
    waitbarN<AINFLIGHT>();                     // B(0) in LDS; A(0) in flight

#pragma unroll
    for (int kt = 0; kt < NKT; ++kt) {
        if (kt + 1 < NKT) {
            stageB(kt + 1, (kt + 1) & 1);      // oldest VMEM this tile
            __builtin_amdgcn_sched_barrier(0); // keep A-loads newest
            if (((kt + 1) & 1) == 0) loadA(kt + 1, A0h, A0l, F0);
            else                     loadA(kt + 1, A1h, A1l, F1);
        }

        short8 ah[MF], al[MF];
        if constexpr (ASPLIT) {
            if ((kt & 1) == 0) {
#pragma unroll
                for (int mf = 0; mf < MF; ++mf) { ah[mf] = A0h[mf]; al[mf] = A0l[mf]; }
            } else {
#pragma unroll
                for (int mf = 0; mf < MF; ++mf) { ah[mf] = A1h[mf]; al[mf] = A1l[mf]; }
            }
        } else {
            const auto& Fc = (kt & 1) ? F1 : F0;
#pragma unroll
            for (int mf = 0; mf < MF; ++mf) {
                short8 h8, l8;
#pragma unroll
                for (int e = 0; e < 8; ++e) {
                    float f = (e < 4) ? (&Fc[mf][0].x)[e] : (&Fc[mf][1].x)[e - 4];
                    ushort hh = f2bf(f);
                    h8[e] = (short)hh;
                    l8[e] = (short)f2bf(f - bf2f(hh));
                }
                ah[mf] = h8; al[mf] = l8;
            }
        }

        const int cb = kt & 1;
#pragma unroll
        for (int nf = 0; nf < NF; ++nf) {
            int bslot = lq * NTOT + nf * 16 + lc;
            short8 bh = *(const short8*)&Bh[cb][bslot * 8];
            short8 bl = *(const short8*)&Bl[cb][bslot * 8];
#pragma unroll
            for (int mf = 0; mf < MF; ++mf) {
                acc[mf][nf] = __builtin_amdgcn_mfma_f32_16x16x32_bf16(ah[mf], bh, acc[mf][nf], 0, 0, 0);
                acc[mf][nf] = __builtin_amdgcn_mfma_f32_16x16x32_bf16(ah[mf], bl, acc[mf][nf], 0, 0, 0);
                acc[mf][nf] = __builtin_amdgcn_mfma_f32_16x16x32_bf16(al[mf], bh, acc[mf][nf], 0, 0, 0);
            }
        }
        if (kt + 1 < NKT) waitbarN<AINFLIGHT>();  // B(t+1) landed; A(t+1) flying
    }

    // ---- attention-logit epilogue (f32 accumulator — full precision) ----
    if constexpr (AHH > 0) {
        constexpr int FPH = ACC / 16;     // frags per head
        constexpr int NG  = ATTN / ACC;   // heads (all live in this wave)
#pragma unroll
        for (int g = 0; g < NG; ++g) {
#pragma unroll
            for (int mf = 0; mf < MF; ++mf) {
                float ps[4] = {0.f, 0.f, 0.f, 0.f};
                float pd[4] = {0.f, 0.f, 0.f, 0.f};
#pragma unroll
                for (int j = 0; j < FPH; ++j) {
                    int col = g * ACC + j * 16 + lc;
                    float av = a_src[col], dv = a_dst[col];
#pragma unroll
                    for (int r = 0; r < 4; ++r) {
                        ps[r] = fmaf(acc[mf][g * FPH + j][r], av, ps[r]);
                        pd[r] = fmaf(acc[mf][g * FPH + j][r], dv, pd[r]);
                    }
                }
#pragma unroll
                for (int off = 1; off < 16; off <<= 1)
#pragma unroll
                    for (int r = 0; r < 4; ++r) {
                        ps[r] += __shfl_xor(ps[r], off);
                        pd[r] += __shfl_xor(pd[r], off);
                    }
                if (lc == 0) {
#pragma unroll
                    for (int r = 0; r < 4; ++r) {
                        int row = wrow + mf * 16 + lq * 4 + r;
                        if (row < n) {
                            als[(size_t)row * AHH + g] = ps[r];
                            ald[(size_t)row * AHH + g] = pd[r];
                        }
                    }
                }
            }
        }
    }

    // ---- store (+ bias for cols >= BIAS_OFF); Y1/Y2 optionally bf16 ----
#pragma unroll
    for (int mf = 0; mf < MF; ++mf) {
        int rb4 = wrow + mf * 16 + lq * 4;
#pragma unroll
        for (int nf = 0; nf < NF; ++nf) {
            int col = nf * 16 + lc;
            float bv = 0.f;
            if constexpr (BIAS_OFF < NTOT) {
                if (col >= BIAS_OFF) bv = bias[col - BIAS_OFF];
            }
#pragma unroll
            for (int r = 0; r < 4; ++r) {
                int row = rb4 + r;
                if (row < n) {
                    float v = acc[mf][nf][r] + bv;
                    if (col < CSPLIT) {
                        if constexpr (Y1BF)
                            ((ushort*)Y1)[(size_t)row * ldy1 + col] = f2bf(v);
                        else
                            ((float*)Y1)[(size_t)row * ldy1 + col] = v;
                    } else {
                        if constexpr (Y2BF)
                            ((ushort*)Y2)[(size_t)row * ldy2 + (col - CSPLIT)] = f2bf(v);
                        else
                            ((float*)Y2)[(size_t)row * ldy2 + (col - CSPLIT)] = v;
                    }
                }
            }
        }
    }
}

// ---------------------------------------------------------------------------
// CSR build: histogram -> block sums -> scan sums -> per-block scan -> fill
// ---------------------------------------------------------------------------
__global__ void deg_kernel(const int* __restrict__ ei, int* __restrict__ deg)
{
    int t = blockIdx.x * blockDim.x + threadIdx.x;
    if (t < NE) atomicAdd(&deg[ei[NE + t]], 1);   // dst of edge t
}

__global__ void block_sum_kernel(const int* __restrict__ deg, int* __restrict__ bsum)
{
    int node = blockIdx.x * 256 + threadIdx.x;
    int v = (node < NN) ? deg[node] + 1 : 0;      // +1 = self loop
#pragma unroll
    for (int off = 32; off > 0; off >>= 1) v += __shfl_down(v, off);
    __shared__ int sh[4];
    if ((threadIdx.x & 63) == 0) sh[threadIdx.x >> 6] = v;
    __syncthreads();
    if (threadIdx.x == 0) bsum[blockIdx.x] = sh[0] + sh[1] + sh[2] + sh[3];
}

__global__ void scan_sums_kernel(const int* __restrict__ bsum, int* __restrict__ bsumx,
                                 int* __restrict__ rowptr)
{
    if (threadIdx.x == 0) {
        int run = 0;
        for (int i = 0; i < NB; ++i) { bsumx[i] = run; run += bsum[i]; }
        rowptr[NN] = run;    // == EP
    }
}

__global__ void scan_blocks_kernel(const int* __restrict__ deg, const int* __restrict__ bsumx,
                                   int* __restrict__ rowptr, int* __restrict__ cursor)
{
    __shared__ int sh[256];
    int node = blockIdx.x * 256 + threadIdx.x;
    int v = (node < NN) ? deg[node] + 1 : 0;
    sh[threadIdx.x] = v;
    __syncthreads();
#pragma unroll
    for (int off = 1; off < 256; off <<= 1) {
        int tv = (threadIdx.x >= off) ? sh[threadIdx.x - off] : 0;
        __syncthreads();
        sh[threadIdx.x] += tv;
        __syncthreads();
    }
    if (node < NN) {
        int excl = bsumx[blockIdx.x] + sh[threadIdx.x] - v;
        rowptr[node] = excl;
        cursor[node] = excl;
    }
}

__global__ void fill_kernel(const int* __restrict__ ei, int* __restrict__ cursor,
                            int* __restrict__ csr_src)
{
    int t = blockIdx.x * blockDim.x + threadIdx.x;
    if (t >= EP) return;
    int s, d;
    if (t < NE) { s = ei[t]; d = ei[NE + t]; }
    else        { s = d = t - NE; }
    int pos = atomicAdd(&cursor[d], 1);
    csr_src[pos] = s;
}

// ---------------------------------------------------------------------------
// Softmax stats + normalized edge weights (packed bf16). ONE THREAD PER NODE.
// ---------------------------------------------------------------------------
template<int HH>
__global__ __launch_bounds__(256)
void attn_weights_kernel(const int* __restrict__ rowptr, const int* __restrict__ csr_src,
                         const float* __restrict__ als, const float* __restrict__ ald,
                         ushort* __restrict__ wq, int n)
{
    int node = blockIdx.x * 256 + threadIdx.x;
    if (node >= n) return;
    const int e0 = rowptr[node], e1 = rowptr[node + 1];
    float aldv[HH], m[HH], d[HH];
#pragma unroll
    for (int h = 0; h < HH; ++h) { m[h] = -1e30f; d[h] = 0.f; }
    if constexpr (HH == 4) {
        float4 a = *(const float4*)&ald[(size_t)node * 4];
        aldv[0] = a.x; aldv[1] = a.y; aldv[2] = a.z; aldv[3] = a.w;
    } else {
        aldv[0] = ald[node];
    }
    for (int e = e0; e < e1; ++e) {
        int s = csr_src[e];
        float av[HH];
        if constexpr (HH == 4) {
            float4 a = *(const float4*)&als[(size_t)s * 4];
            av[0] = a.x; av[1] = a.y; av[2] = a.z; av[3] = a.w;
        } else {
            av[0] = als[s];
        }
#pragma unroll
        for (int h = 0; h < HH; ++h) {
            float sc = leaky(av[h] + aldv[h]);
            float nm = fmaxf(m[h], sc);
            d[h] = d[h] * __expf(m[h] - nm) + __expf(sc - nm);
            m[h] = nm;
        }
    }
#pragma unroll
    for (int h = 0; h < HH; ++h) d[h] = 1.f / d[h];
    for (int e = e0; e < e1; ++e) {
        int s = csr_src[e];
        float av[HH];
        if constexpr (HH == 4) {
            float4 a = *(const float4*)&als[(size_t)s * 4];
            av[0] = a.x; av[1] = a.y; av[2] = a.z; av[3] = a.w;
        } else {
            av[0] = als[s];
        }
        if constexpr (HH == 4) {
            uint2 o;
            unsigned int w0 = f2bf(__expf(leaky(av[0] + aldv[0]) - m[0]) * d[0]);
            unsigned int w1 = f2bf(__expf(leaky(av[1] + aldv[1]) - m[1]) * d[1]);
            unsigned int w2 = f2bf(__expf(leaky(av[2] + aldv[2]) - m[2]) * d[2]);
            unsigned int w3 = f2bf(__expf(leaky(av[3] + aldv[3]) - m[3]) * d[3]);
            o.x = w0 | (w1 << 16);
            o.y = w2 | (w3 << 16);
            *(uint2*)&wq[(size_t)e * 4] = o;
        } else {
            wq[e] = f2bf(__expf(leaky(av[0] + aldv[0]) - m[0]) * d[0]);
        }
    }
}

// ---------------------------------------------------------------------------
// Weighted gather-SpMM + fused epilogue. ONE WAVE PER NODE, lane = channel
// pair. xh gathered as bf16; wq read as bf16. 4-edge unroll for load ILP.
// Output pre-split hi/lo bf16. RESMODE: 0 = f32, 1 = split hi/lo, 2 = bf16.
// ---------------------------------------------------------------------------
template<int HH, int CC, bool DOELU, int RESMODE>
__global__ __launch_bounds__(256)
void spmm_kernel(const int* __restrict__ rowptr, const int* __restrict__ csr_src,
                 const ushort* __restrict__ xh, const ushort* __restrict__ wq,
                 const float* __restrict__ b,
                 const float* __restrict__ resf,
                 const ushort* __restrict__ resh, const ushort* __restrict__ resl,
                 ushort* __restrict__ outh, ushort* __restrict__ outl, int n)
{
    constexpr int HCL = HH * CC;
    constexpr int CPL = HCL / 64;                 // channels per lane (2 or 1)
    const int l = threadIdx.x & 63;
    const int node = blockIdx.x * 4 + (threadIdx.x >> 6);
    if (node >= n) return;
    const int c = l * CPL;
    const int h = c / CC;
    const int e0 = rowptr[node], e1 = rowptr[node + 1];

    float a0[CPL], a1[CPL];
#pragma unroll
    for (int j = 0; j < CPL; ++j) { a0[j] = 0.f; a1[j] = 0.f; }

    auto gather = [&](int e, float* accv) {
        int s = csr_src[e];
        float w0 = bf2f(wq[(size_t)e * HH + h]);
        if constexpr (CPL == 2) {
            unsigned int uv = *(const unsigned int*)&xh[(size_t)s * HCL + c];
            accv[0] = fmaf(w0, bf2f((ushort)(uv & 0xffffu)), accv[0]);
            accv[1] = fmaf(w0, bf2f((ushort)(uv >> 16)), accv[1]);
        } else {
            accv[0] = fmaf(w0, bf2f(xh[(size_t)s * HCL + c]), accv[0]);
        }
    };

    int e = e0;
    for (; e + 3 < e1; e += 4) {
        gather(e, a0); gather(e + 1, a1);
        gather(e + 2, a0); gather(e + 3, a1);
    }
    for (; e < e1; ++e) gather(e, a0);

#pragma unroll
    for (int j = 0; j < CPL; ++j) {
        size_t idx = (size_t)node * HCL + c + j;
        float rv;
        if constexpr (RESMODE == 1) rv = bf2f(resh[idx]) + bf2f(resl[idx]);
        else if constexpr (RESMODE == 2) rv = bf2f(resh[idx]);
        else rv = resf[idx];
        float v = a0[j] + a1[j] + b[c + j] + rv;
        if (DOELU) v = v > 0.f ? v : (__expf(v) - 1.f);
        ushort hh = f2bf(v);
        outh[idx] = hh;
        outl[idx] = f2bf(v - bf2f(hh));
    }
}

// ---------------------------------------------------------------------------
extern "C" void kernel_launch(void* const* d_in, const int* in_sizes, int n_in,
                              void* d_out, int out_size, void* d_ws, size_t ws_size,
                              hipStream_t stream)
{
    const float* x    = (const float*)d_in[0];
    const int*   ei   = (const int*)d_in[1];
    const float* W0   = (const float*)d_in[2];
    const float* b0   = (const float*)d_in[3];
    const float* as0  = (const float*)d_in[4];
    const float* ad0  = (const float*)d_in[5];
    const float* W1   = (const float*)d_in[6];
    const float* b1   = (const float*)d_in[7];
    const float* as1  = (const float*)d_in[8];
    const float* ad1  = (const float*)d_in[9];
    const float* W2   = (const float*)d_in[10];
    const float* b2   = (const float*)d_in[11];
    const float* as2  = (const float*)d_in[12];
    const float* ad2  = (const float*)d_in[13];
    const float* sk0W = (const float*)d_in[14];
    const float* sk0b = (const float*)d_in[15];
    const float* sk2W = (const float*)d_in[16];
    const float* sk2b = (const float*)d_in[17];
    const float* jkW  = (const float*)d_in[18];
    const float* jkb  = (const float*)d_in[19];
    float* out = (float*)d_out;

    float* ws = (float*)d_ws;
    size_t off = 0;
    float* s_xh  = ws + off; off += (size_t)NN * 128;   // xh out (bf16 used as u16)
    float* s_r0  = ws + off; off += (size_t)NN * 128;   // res0/res2 (bf16 view)
    float* s_als = ws + off; off += (size_t)NN * 4;
    float* s_ald = ws + off; off += (size_t)NN * 4;
    ushort* u_wq = (ushort*)(ws + off); off += (size_t)EP * 2;   // packed bf16 wq
    ushort* s_xhb = (ushort*)s_xh;                      // bf16 view
    ushort* s_r0b = (ushort*)s_r0;                      // bf16 view of residual
    // split-bf16 activations (hi/lo), consumed by downstream GEMMs
    ushort* u_x0h = (ushort*)(ws + off); off += (size_t)NN * 64;   // [NN][128] u16
    ushort* u_x0l = (ushort*)(ws + off); off += (size_t)NN * 64;
    ushort* u_x1h = (ushort*)(ws + off); off += (size_t)NN * 64;
    ushort* u_x1l = (ushort*)(ws + off); off += (size_t)NN * 64;
    ushort* u_h2h = (ushort*)(ws + off); off += (size_t)NN * 32;   // [NN][64] u16
    ushort* u_h2l = (ushort*)(ws + off); off += (size_t)NN * 32;
    int* i_deg    = (int*)(ws + off); off += NN;
    int* i_rowptr = (int*)(ws + off); off += NN + 1;
    int* i_cursor = (int*)(ws + off); off += NN;
    int* i_csrsrc = (int*)(ws + off); off += EP;
    int* i_bsum   = (int*)(ws + off); off += NB;
    int* i_bsumx  = (int*)(ws + off); off += NB;
    off = (off + 3) & ~(size_t)3;     // 16B-align the bf16 weight tiles
    ushort* wt0h = (ushort*)(ws + off); off += 32768;   // 8*256*32 u16
    ushort* wt0l = (ushort*)(ws + off); off += 32768;
    ushort* wt1h = (ushort*)(ws + off); off += 8192;    // 4*128*32 u16
    ushort* wt1l = (ushort*)(ws + off); off += 8192;
    ushort* wt2h = (ushort*)(ws + off); off += 8192;    // 4*128*32 u16
    ushort* wt2l = (ushort*)(ws + off); off += 8192;
    ushort* wtjh = (ushort*)(ws + off); off += 10240;   // 10*64*32 u16
    ushort* wtjl = (ushort*)(ws + off); off += 10240;

    const int G128 = (NN + 127) / 128;    // 782 row blocks (128 rows each)
    const int GN = (NN + 255) / 256;      // node-thread blocks
    const int GS = (NN + 3) / 4;          // node-wave blocks
    constexpr int BIG = 1 << 30;

    // ======================= CSR build (shared by all 3 layers) ==========
    hipMemsetAsync(i_deg, 0, (size_t)NN * sizeof(int), stream);
    deg_kernel<<<(NE + 255) / 256, 256, 0, stream>>>(ei, i_deg);
    block_sum_kernel<<<NB, 256, 0, stream>>>(i_deg, i_bsum);
    scan_sums_kernel<<<1, 64, 0, stream>>>(i_bsum, i_bsumx, i_rowptr);
    scan_blocks_kernel<<<NB, 256, 0, stream>>>(i_deg, i_bsumx, i_rowptr, i_cursor);
    fill_kernel<<<(EP + 255) / 256, 256, 0, stream>>>(ei, i_cursor, i_csrsrc);

    // ======================= weight pre-tiling (split bf16) ==============
    pretile_kernel<<<256, 256, 0, stream>>>(W0, sk0W, 256, 128, 256, wt0h, wt0l);
    pretile_kernel<<<64,  256, 0, stream>>>(W1, nullptr, 128, 128, 128, wt1h, wt1l);
    pretile_kernel<<<64,  256, 0, stream>>>(W2, sk2W, 128, 64, 128, wt2h, wt2l);
    pretile_kernel<<<80,  256, 0, stream>>>(jkW, nullptr, 320, 64, 64, wtjh, wtjl);

    // ======= layer 0: fused [xh0 | res0] = x @ [W0 | sk0W] (K=256, N=256)
    //         MF=1: 8 waves x 16 rows, 512 thr; Y1 and Y2 (res0) bf16
    gemm_mfma<256, 256, 1, 256, 256, 128, 128, 4, 32, 128, false, true, true, 4>
        <<<G128, 512, 0, stream>>>(
        x, nullptr, nullptr, nullptr, nullptr, nullptr, 256, 0, 0,
        wt0h, wt0l, sk0b,
        s_xhb, s_r0b, 128, 128, s_als, s_ald, as0, ad0, NN);
    attn_weights_kernel<4><<<GN, 256, 0, stream>>>(
        i_rowptr, i_csrsrc, s_als, s_ald, u_wq, NN);
    spmm_kernel<4, 32, true, 2><<<GS, 256, 0, stream>>>(
        i_rowptr, i_csrsrc, s_xhb, u_wq, b0, nullptr, s_r0b, nullptr,
        u_x0h, u_x0l, NN);

    // ======= layer 1: xh1 = x0 @ W1 (K=128, N=128; split-bf16 A input)
    gemm_mfma<128, 128, 2, 128, 128, 128, BIG, 4, 32, 128, true, true, false, 3>
        <<<G128, 256, 0, stream>>>(
        u_x0h, u_x0l, nullptr, nullptr, nullptr, nullptr, 128, 0, 0,
        wt1h, wt1l, nullptr,
        s_xhb, nullptr, 128, 0, s_als, s_ald, as1, ad1, NN);
    attn_weights_kernel<4><<<GN, 256, 0, stream>>>(
        i_rowptr, i_csrsrc, s_als, s_ald, u_wq, NN);
    spmm_kernel<4, 32, true, 1><<<GS, 256, 0, stream>>>(
        i_rowptr, i_csrsrc, s_xhb, u_wq, b1, nullptr, u_x0h, u_x0l,
        u_x1h, u_x1l, NN);

    // ======= layer 2: fused [xh2 | res2] = x1 @ [W2 | sk2W] (K=128, N=128)
    //         Y2 (res2) bf16
    gemm_mfma<128, 128, 2, 128, 128, 64, 64, 1, 64, 64, true, true, true, 3>
        <<<G128, 256, 0, stream>>>(
        u_x1h, u_x1l, nullptr, nullptr, nullptr, nullptr, 128, 0, 0,
        wt2h, wt2l, sk2b,
        s_xhb, s_r0b, 64, 64, s_als, s_ald, as2, ad2, NN);
    attn_weights_kernel<1><<<GN, 256, 0, stream>>>(
        i_rowptr, i_csrsrc, s_als, s_ald, u_wq, NN);
    spmm_kernel<1, 64, false, 2><<<GS, 256, 0, stream>>>(
        i_rowptr, i_csrsrc, s_xhb, u_wq, b2, nullptr, s_r0b, nullptr,
        u_h2h, u_h2l, NN);

    // ======= JumpingKnowledge: out = [x0|x1|h2] @ jkW + jkb (K=320, N=64)
    gemm_mfma<320, 64, 2, 128, 256, 64, 0, 0, 16, 0, true, false, false, 3>
        <<<G128, 256, 0, stream>>>(
        u_x0h, u_x0l, u_x1h, u_x1l, u_h2h, u_h2l, 128, 128, 64,
        wtjh, wtjl, jkb,
        out, nullptr, 64, 0, nullptr, nullptr, nullptr, nullptr, NN);
}